// Round 1
// baseline (372.737 us; speedup 1.0000x reference)
//
#include <hip/hip_runtime.h>
#include <hip/hip_bf16.h>

typedef unsigned short u16;
typedef unsigned int u32;
typedef __bf16 bf16x8 __attribute__((ext_vector_type(8)));
typedef float f32x4 __attribute__((ext_vector_type(4)));

#define NX 8192
#define NY 8192
#define D  512
#define BM 128
#define BN 128
#define BK 64

// fp32 -> bf16 round-to-nearest-even (inputs are finite normals; no NaN path needed)
__device__ __forceinline__ u16 f2bf(float f) {
    u32 u = __builtin_bit_cast(u32, f);
    u = (u + 0x7FFFu + ((u >> 16) & 1u)) >> 16;
    return (u16)u;
}

// async global->LDS, 16B per lane. LDS dst must be wave-uniform base; global src is per-lane.
__device__ __forceinline__ void async16(u16* lds, const u16* g) {
    __builtin_amdgcn_global_load_lds(
        (const __attribute__((address_space(1))) void*)g,
        (__attribute__((address_space(3))) void*)lds,
        16, 0, 0);
}

// One block per row (16384 rows total: first 8192 = x, next 8192 = y).
// Cast fp32 -> bf16 into ws, compute fp32 squared row norms.
__global__ __launch_bounds__(256) void prep_kernel(
    const float* __restrict__ x, const float* __restrict__ y,
    u16* __restrict__ xb, u16* __restrict__ yb,
    float* __restrict__ x2, float* __restrict__ y2)
{
    const int t = threadIdx.x;
    const int row = blockIdx.x;
    const float* src;
    u16* dst;
    float* nrm;
    if (row < NX) {
        src = x + (size_t)row * D; dst = xb + (size_t)row * D; nrm = x2 + row;
    } else {
        const int r = row - NX;
        src = y + (size_t)r * D; dst = yb + (size_t)r * D; nrm = y2 + r;
    }
    // 512 cols / 256 threads = 2 per thread
    float2 v = *(const float2*)(src + t * 2);
    float s = v.x * v.x + v.y * v.y;
    u32 packed = (u32)f2bf(v.x) | ((u32)f2bf(v.y) << 16);
    ((u32*)dst)[t] = packed;

    // wave (64) reduce then cross-wave via LDS
    #pragma unroll
    for (int o = 32; o > 0; o >>= 1) s += __shfl_down(s, o);
    __shared__ float red[4];
    if ((t & 63) == 0) red[t >> 6] = s;
    __syncthreads();
    if (t == 0) *nrm = red[0] + red[1] + red[2] + red[3];
}

// 128x128 tile, BK=64, 4 waves (2x2 of 64x64), 16x16x32 bf16 MFMA, 4x4 frags/wave.
// global_load_lds width=16 staging into linear LDS; fused RBF epilogue.
__global__ __launch_bounds__(256) void rbf_kernel(
    const u16* __restrict__ xb, const u16* __restrict__ yb,
    const float* __restrict__ x2, const float* __restrict__ y2,
    const float* __restrict__ gamma_p, float* __restrict__ out)
{
    __shared__ u16 As[BM * BK];   // 16 KiB
    __shared__ u16 Bs[BN * BK];   // 16 KiB

    const int t    = threadIdx.x;
    const int lane = t & 63;
    const int wid  = t >> 6;          // 0..3
    const int wr   = wid >> 1;        // 0..1 (row half)
    const int wc   = wid & 1;         // 0..1 (col half)

    // XCD-aware bijective swizzle (nwg = 4096, % 8 == 0)
    const int nwg = gridDim.x;
    const int cpx = nwg >> 3;
    const int bid = blockIdx.x;
    const int swz = (bid & 7) * cpx + (bid >> 3);
    const int brow = swz >> 6;        // grid is 64 x 64 tiles
    const int bcol = swz & 63;

    const size_t row0 = (size_t)brow * BM;
    const size_t col0 = (size_t)bcol * BN;

    f32x4 acc[4][4] = {};

    // staging geometry: chunk = 1024 B = 8 rows x 64 cols(bf16). 16 chunks per tile.
    // wave w stages chunks [w*4, w*4+4). lane covers 16B: row += lane>>3, col = (lane&7)*8
    const int c0 = wid * 4;
    const int lr = lane >> 3;
    const int lc = (lane & 7) * 8;

    for (int kt = 0; kt < D; kt += BK) {
        __syncthreads();   // previous compute done before overwrite
        #pragma unroll
        for (int i = 0; i < 4; ++i) {
            const int c = c0 + i;
            async16(&As[c * 512], xb + (row0 + (size_t)(c * 8 + lr)) * D + kt + lc);
        }
        #pragma unroll
        for (int i = 0; i < 4; ++i) {
            const int c = c0 + i;
            async16(&Bs[c * 512], yb + (col0 + (size_t)(c * 8 + lr)) * D + kt + lc);
        }
        __syncthreads();   // compiler drains vmcnt before s_barrier -> staging visible

        #pragma unroll
        for (int ks = 0; ks < 2; ++ks) {
            bf16x8 a[4], b[4];
            const int ko = ks * 32 + (lane >> 4) * 8;
            #pragma unroll
            for (int m = 0; m < 4; ++m)
                a[m] = *(const bf16x8*)&As[(wr * 64 + m * 16 + (lane & 15)) * BK + ko];
            #pragma unroll
            for (int n = 0; n < 4; ++n)
                b[n] = *(const bf16x8*)&Bs[(wc * 64 + n * 16 + (lane & 15)) * BK + ko];
            #pragma unroll
            for (int m = 0; m < 4; ++m)
                #pragma unroll
                for (int n = 0; n < 4; ++n)
                    acc[m][n] = __builtin_amdgcn_mfma_f32_16x16x32_bf16(a[m], b[n], acc[m][n], 0, 0, 0);
        }
    }

    // epilogue: out[i][j] = exp(-gamma * max(x2[i] + y2[j] - 2*dot, 0))
    const float gamma = *gamma_p;
    const int rl = (lane >> 4) * 4;   // C/D: row = (lane>>4)*4 + reg, col = lane&15
    const int cl = lane & 15;
    #pragma unroll
    for (int m = 0; m < 4; ++m) {
        #pragma unroll
        for (int j = 0; j < 4; ++j) {
            const size_t gr = row0 + wr * 64 + m * 16 + rl + j;
            const float xn = x2[gr];
            float* orow = out + gr * (size_t)NY + col0 + wc * 64 + cl;
            #pragma unroll
            for (int n = 0; n < 4; ++n) {
                const float yn = y2[col0 + wc * 64 + n * 16 + cl];
                float sq = xn + yn - 2.0f * acc[m][n][j];
                sq = fmaxf(sq, 0.0f);
                orow[n * 16] = __expf(-gamma * sq);
            }
        }
    }
}

extern "C" void kernel_launch(void* const* d_in, const int* in_sizes, int n_in,
                              void* d_out, int out_size, void* d_ws, size_t ws_size,
                              hipStream_t stream) {
    const float* x = (const float*)d_in[0];
    const float* y = (const float*)d_in[1];
    const float* gamma_p = (const float*)d_in[2];
    float* out = (float*)d_out;

    // ws layout: xb[8192*512] bf16 | yb[8192*512] bf16 | x2[8192] f32 | y2[8192] f32
    u16* xb = (u16*)d_ws;
    u16* yb = xb + (size_t)NX * D;
    float* x2 = (float*)(yb + (size_t)NY * D);
    float* y2 = x2 + NX;

    prep_kernel<<<NX + NY, 256, 0, stream>>>(x, y, xb, yb, x2, y2);

    const int grid = (NX / BM) * (NY / BN);   // 64 * 64 = 4096
    rbf_kernel<<<grid, 256, 0, stream>>>(xb, yb, x2, y2, gamma_p, out);
}

// Round 2
// 333.677 us; speedup vs baseline: 1.1171x; 1.1171x over previous
//
#include <hip/hip_runtime.h>
#include <hip/hip_bf16.h>

typedef unsigned char u8;
typedef unsigned short u16;
typedef unsigned int u32;
typedef int i32x8 __attribute__((ext_vector_type(8)));
typedef float f32x4 __attribute__((ext_vector_type(4)));

#define NX 8192
#define NY 8192
#define D  512
#define BM 128
#define BN 128
#define BK 128   // fp8 elems (=bytes) per K-tile; one 16x16x128 MFMA spans it

#define SCALE_ONE 0x7F7F7F7F  // E8M0 127 = 2^0 in every byte -> any opsel picks 1.0

// async global->LDS, 16B per lane. LDS dst is wave-uniform base + lane*16.
__device__ __forceinline__ void async16(void* lds, const void* g) {
    __builtin_amdgcn_global_load_lds(
        (const __attribute__((address_space(1))) void*)g,
        (__attribute__((address_space(3))) void*)lds,
        16, 0, 0);
}

// One block (128 thr) per row (16384 rows: first 8192 = x, rest = y).
// fp32 -> fp8 e4m3 (HW cvt) into ws + exact fp32 squared row norm.
__global__ __launch_bounds__(128) void prep_kernel(
    const float* __restrict__ x, const float* __restrict__ y,
    u8* __restrict__ xq, u8* __restrict__ yq,
    float* __restrict__ x2, float* __restrict__ y2)
{
    const int t = threadIdx.x;
    const int row = blockIdx.x;
    const float* src; u8* dst; float* nrm;
    if (row < NX) {
        src = x + (size_t)row * D; dst = xq + (size_t)row * D; nrm = x2 + row;
    } else {
        const int r = row - NX;
        src = y + (size_t)r * D; dst = yq + (size_t)r * D; nrm = y2 + r;
    }
    // 512 cols / 128 threads = 4 per thread
    float4 v = *(const float4*)(src + t * 4);
    float s = v.x * v.x + v.y * v.y + v.z * v.z + v.w * v.w;  // norm from ORIGINAL fp32
    u32 p = 0;
    p = __builtin_amdgcn_cvt_pk_fp8_f32(v.x, v.y, p, false);  // bytes 0,1
    p = __builtin_amdgcn_cvt_pk_fp8_f32(v.z, v.w, p, true);   // bytes 2,3
    ((u32*)dst)[t] = p;

    #pragma unroll
    for (int o = 32; o > 0; o >>= 1) s += __shfl_down(s, o);
    __shared__ float red[2];
    if ((t & 63) == 0) red[t >> 6] = s;
    __syncthreads();
    if (t == 0) *nrm = red[0] + red[1];
}

// 128x128 tile, BK=128 fp8, 4 waves (2x2 of 64x64), mfma_scale 16x16x128 f8f6f4
// with unit scales, 4x4 frags/wave. Same verified m97 2-barrier structure and
// staging geometry as the bf16 round-1 kernel (16 KiB tiles, 1024B chunks).
__global__ __launch_bounds__(256) void rbf_kernel(
    const u8* __restrict__ xq, const u8* __restrict__ yq,
    const float* __restrict__ x2, const float* __restrict__ y2,
    const float* __restrict__ gamma_p, float* __restrict__ out)
{
    __shared__ u8 As[BM * BK];   // 16 KiB
    __shared__ u8 Bs[BN * BK];   // 16 KiB

    const int t    = threadIdx.x;
    const int lane = t & 63;
    const int wid  = t >> 6;          // 0..3
    const int wr   = wid >> 1;        // row half
    const int wc   = wid & 1;         // col half

    // XCD-aware bijective swizzle (nwg = 4096, % 8 == 0)
    const int nwg = gridDim.x;
    const int cpx = nwg >> 3;
    const int bid = blockIdx.x;
    const int swz = (bid & 7) * cpx + (bid >> 3);
    const int brow = swz >> 6;        // 64 x 64 tile grid
    const int bcol = swz & 63;

    const size_t row0 = (size_t)brow * BM;
    const size_t col0 = (size_t)bcol * BN;

    f32x4 acc[4][4] = {};

    // staging: chunk = 1024 B = 8 rows x 128 B. 16 chunks/tile, wave stages 4.
    // lane covers 16B: row += lane>>3, colbyte = (lane&7)*16
    const int c0 = wid * 4;
    const int lr = lane >> 3;
    const int lc = (lane & 7) * 16;

    for (int kt = 0; kt < D; kt += BK) {
        __syncthreads();   // previous compute's LDS reads done before overwrite
        #pragma unroll
        for (int i = 0; i < 4; ++i) {
            const int c = c0 + i;
            async16(&As[c * 1024], xq + (row0 + (size_t)(c * 8 + lr)) * D + kt + lc);
        }
        #pragma unroll
        for (int i = 0; i < 4; ++i) {
            const int c = c0 + i;
            async16(&Bs[c * 1024], yq + (col0 + (size_t)(c * 8 + lr)) * D + kt + lc);
        }
        __syncthreads();   // compiler drains vmcnt before s_barrier -> staging visible

        // fragments: A row = lane&15 (+16*m), k = (lane>>4)*32 + [0..31] bytes
        const int ko = (lane >> 4) * 32;
        i32x8 a[4], b[4];
        #pragma unroll
        for (int m = 0; m < 4; ++m)
            a[m] = *(const i32x8*)&As[(wr * 64 + m * 16 + (lane & 15)) * BK + ko];
        #pragma unroll
        for (int n = 0; n < 4; ++n)
            b[n] = *(const i32x8*)&Bs[(wc * 64 + n * 16 + (lane & 15)) * BK + ko];
        #pragma unroll
        for (int m = 0; m < 4; ++m)
            #pragma unroll
            for (int n = 0; n < 4; ++n)
                acc[m][n] = __builtin_amdgcn_mfma_scale_f32_16x16x128_f8f6f4(
                    a[m], b[n], acc[m][n],
                    0 /*cbsz: A=fp8*/, 0 /*blgp: B=fp8*/,
                    0, SCALE_ONE, 0, SCALE_ONE);
    }

    // epilogue: out[i][j] = exp(-gamma * max(x2[i] + y2[j] - 2*dot, 0))
    const float gamma = *gamma_p;
    const int rl = (lane >> 4) * 4;   // C/D: row = (lane>>4)*4 + reg, col = lane&15
    const int cl = lane & 15;
    #pragma unroll
    for (int m = 0; m < 4; ++m) {
        #pragma unroll
        for (int j = 0; j < 4; ++j) {
            const size_t gr = row0 + wr * 64 + m * 16 + rl + j;
            const float xn = x2[gr];
            float* orow = out + gr * (size_t)NY + col0 + wc * 64 + cl;
            #pragma unroll
            for (int n = 0; n < 4; ++n) {
                const float yn = y2[col0 + wc * 64 + n * 16 + cl];
                float sq = xn + yn - 2.0f * acc[m][n][j];
                sq = fmaxf(sq, 0.0f);
                orow[n * 16] = __expf(-gamma * sq);
            }
        }
    }
}

extern "C" void kernel_launch(void* const* d_in, const int* in_sizes, int n_in,
                              void* d_out, int out_size, void* d_ws, size_t ws_size,
                              hipStream_t stream) {
    const float* x = (const float*)d_in[0];
    const float* y = (const float*)d_in[1];
    const float* gamma_p = (const float*)d_in[2];
    float* out = (float*)d_out;

    // ws layout: xq[8192*512] u8 | yq[8192*512] u8 | x2[8192] f32 | y2[8192] f32
    u8* xq = (u8*)d_ws;
    u8* yq = xq + (size_t)NX * D;
    float* x2 = (float*)(yq + (size_t)NY * D);
    float* y2 = x2 + NX;

    prep_kernel<<<NX + NY, 128, 0, stream>>>(x, y, xq, yq, x2, y2);

    const int grid = (NX / BM) * (NY / BN);   // 64 * 64 = 4096
    rbf_kernel<<<grid, 256, 0, stream>>>(xq, yq, x2, y2, gamma_p, out);
}

// Round 5
// 317.631 us; speedup vs baseline: 1.1735x; 1.0505x over previous
//
#include <hip/hip_runtime.h>
#include <hip/hip_bf16.h>

typedef unsigned char u8;
typedef unsigned short u16;
typedef unsigned int u32;
typedef int i32x8 __attribute__((ext_vector_type(8)));
typedef float f32x4 __attribute__((ext_vector_type(4)));

#define NX 8192
#define NY 8192
#define D  512
#define BM 128
#define BN 128
#define BK 128   // fp8 bytes per K-tile; one 16x16x128 MFMA spans it

#define SCALE_ONE 0x7F7F7F7F  // E8M0 127 = 2^0 in every byte -> any opsel picks 1.0

// async global->LDS, 16B per lane. LDS dst is wave-uniform base + lane*16.
__device__ __forceinline__ void async16(void* lds, const void* g) {
    __builtin_amdgcn_global_load_lds(
        (const __attribute__((address_space(1))) void*)g,
        (__attribute__((address_space(3))) void*)lds,
        16, 0, 0);
}

// One WAVE per row (16384 rows: first 8192 = x, rest = y). No LDS, no barrier.
// fp32 -> fp8 e4m3 (HW cvt) into ws + exact fp32 squared row norm.
__global__ __launch_bounds__(256) void prep_kernel(
    const float* __restrict__ x, const float* __restrict__ y,
    u8* __restrict__ xq, u8* __restrict__ yq,
    float* __restrict__ x2, float* __restrict__ y2)
{
    const int lane = threadIdx.x & 63;
    const int row  = blockIdx.x * 4 + (threadIdx.x >> 6);
    const float* src; u8* dst; float* nrm;
    if (row < NX) {
        src = x + (size_t)row * D; dst = xq + (size_t)row * D; nrm = x2 + row;
    } else {
        const int r = row - NX;
        src = y + (size_t)r * D; dst = yq + (size_t)r * D; nrm = y2 + r;
    }
    // 512 cols / 64 lanes = 8 per lane (two float4)
    float4 v0 = *(const float4*)(src + lane * 8);
    float4 v1 = *(const float4*)(src + lane * 8 + 4);
    float s = v0.x*v0.x + v0.y*v0.y + v0.z*v0.z + v0.w*v0.w
            + v1.x*v1.x + v1.y*v1.y + v1.z*v1.z + v1.w*v1.w;
    u32 p0 = 0, p1 = 0;
    p0 = __builtin_amdgcn_cvt_pk_fp8_f32(v0.x, v0.y, p0, false);
    p0 = __builtin_amdgcn_cvt_pk_fp8_f32(v0.z, v0.w, p0, true);
    p1 = __builtin_amdgcn_cvt_pk_fp8_f32(v1.x, v1.y, p1, false);
    p1 = __builtin_amdgcn_cvt_pk_fp8_f32(v1.z, v1.w, p1, true);
    uint2 pk = make_uint2(p0, p1);
    *(uint2*)(dst + lane * 8) = pk;

    #pragma unroll
    for (int o = 32; o > 0; o >>= 1) s += __shfl_down(s, o);
    if (lane == 0) *nrm = s;
}

// 128x128 tile, BK=128 fp8, 4 waves (2x2 of 64x64), mfma_scale 16x16x128 f8f6f4
// with unit scales. Double-buffered LDS prefetch: stage(t+1) issues BEFORE
// compute(t); single __syncthreads per K-iter (its vmcnt(0)+lgkmcnt(0) drain
// closes both the staging RAW and the buffer-reuse WAR hazards).
__global__ __launch_bounds__(256) void rbf_kernel(
    const u8* __restrict__ xq, const u8* __restrict__ yq,
    const float* __restrict__ x2, const float* __restrict__ y2,
    const float* __restrict__ gamma_p, float* __restrict__ out)
{
    __shared__ u8 As[2][BM * BK];   // 2 x 16 KiB
    __shared__ u8 Bs[2][BN * BK];   // 2 x 16 KiB

    const int t    = threadIdx.x;
    const int lane = t & 63;
    const int wid  = t >> 6;          // 0..3
    const int wr   = wid >> 1;        // row half
    const int wc   = wid & 1;         // col half

    // XCD-aware bijective swizzle (nwg = 4096, % 8 == 0)
    const int nwg = gridDim.x;
    const int cpx = nwg >> 3;
    const int bid = blockIdx.x;
    const int swz = (bid & 7) * cpx + (bid >> 3);
    const int brow = swz >> 6;        // 64 x 64 tile grid
    const int bcol = swz & 63;

    const size_t row0 = (size_t)brow * BM;
    const size_t col0 = (size_t)bcol * BN;

    // staging: chunk = 1024 B = 8 rows x 128 B. 16 chunks/tile, wave stages 4.
    const int c0 = wid * 4;
    const int lr = lane >> 3;
    const int lc = (lane & 7) * 16;

    auto stage = [&](int buf, int kt) {
        #pragma unroll
        for (int i = 0; i < 4; ++i) {
            const int c = c0 + i;
            async16(&As[buf][c * 1024], xq + (row0 + (size_t)(c * 8 + lr)) * D + kt + lc);
        }
        #pragma unroll
        for (int i = 0; i < 4; ++i) {
            const int c = c0 + i;
            async16(&Bs[buf][c * 1024], yq + (col0 + (size_t)(c * 8 + lr)) * D + kt + lc);
        }
    };

    stage(0, 0);
    __syncthreads();   // prologue drain: tile 0 in LDS

    f32x4 acc[4][4] = {};
    const int ko = (lane >> 4) * 32;
    const int ar = (lane & 15);

    #pragma unroll
    for (int kt = 0; kt < 4; ++kt) {
        if (kt < 3) stage((kt + 1) & 1, (kt + 1) * BK);   // prefetch next tile
        const int cur = kt & 1;
        i32x8 a[4], b[4];
        #pragma unroll
        for (int m = 0; m < 4; ++m)
            a[m] = *(const i32x8*)&As[cur][(wr * 64 + m * 16 + ar) * BK + ko];
        #pragma unroll
        for (int n = 0; n < 4; ++n)
            b[n] = *(const i32x8*)&Bs[cur][(wc * 64 + n * 16 + ar) * BK + ko];
        #pragma unroll
        for (int m = 0; m < 4; ++m)
            #pragma unroll
            for (int n = 0; n < 4; ++n)
                acc[m][n] = __builtin_amdgcn_mfma_scale_f32_16x16x128_f8f6f4(
                    a[m], b[n], acc[m][n],
                    0 /*A=fp8*/, 0 /*B=fp8*/,
                    0, SCALE_ONE, 0, SCALE_ONE);
        if (kt < 3) __syncthreads();   // drains prefetch (vmcnt) + read-done (lgkm)
    }

    // epilogue: out[i][j] = exp(-gamma * max(x2[i] + y2[j] - 2*dot, 0))
    // nontemporal: 268 MB write-once stream must not evict input panels from L2
    const float gamma = *gamma_p;
    const int rl = (lane >> 4) * 4;   // C/D: row = (lane>>4)*4 + reg, col = lane&15
    const int cl = lane & 15;
    #pragma unroll
    for (int m = 0; m < 4; ++m) {
        #pragma unroll
        for (int j = 0; j < 4; ++j) {
            const size_t gr = row0 + wr * 64 + m * 16 + rl + j;
            const float xn = x2[gr];
            float* orow = out + gr * (size_t)NY + col0 + wc * 64 + cl;
            #pragma unroll
            for (int n = 0; n < 4; ++n) {
                const float yn = y2[col0 + wc * 64 + n * 16 + cl];
                float sq = xn + yn - 2.0f * acc[m][n][j];
                sq = fmaxf(sq, 0.0f);
                __builtin_nontemporal_store(__expf(-gamma * sq), &orow[n * 16]);
            }
        }
    }
}

extern "C" void kernel_launch(void* const* d_in, const int* in_sizes, int n_in,
                              void* d_out, int out_size, void* d_ws, size_t ws_size,
                              hipStream_t stream) {
    const float* x = (const float*)d_in[0];
    const float* y = (const float*)d_in[1];
    const float* gamma_p = (const float*)d_in[2];
    float* out = (float*)d_out;

    // ws layout: xq[8192*512] u8 | yq[8192*512] u8 | x2[8192] f32 | y2[8192] f32
    u8* xq = (u8*)d_ws;
    u8* yq = xq + (size_t)NX * D;
    float* x2 = (float*)(yq + (size_t)NY * D);
    float* y2 = x2 + NX;

    prep_kernel<<<(NX + NY) / 4, 256, 0, stream>>>(x, y, xq, yq, x2, y2);

    const int grid = (NX / BM) * (NY / BN);   // 64 * 64 = 4096
    rbf_kernel<<<grid, 256, 0, stream>>>(xq, yq, x2, y2, gamma_p, out);
}